// Round 8
// baseline (678.203 us; speedup 1.0000x reference)
//
#include <hip/hip_runtime.h>
#include <hip/hip_cooperative_groups.h>
#include <hip/hip_bf16.h>
#include <stdint.h>

typedef __hip_bfloat16 bf16;
typedef __hip_bfloat162 bf162;

typedef __attribute__((ext_vector_type(8))) short short8;   // 8 bf16 = 4 VGPRs
typedef __attribute__((ext_vector_type(4))) float floatx4;  // MFMA accumulator

#define BSH   8        // bucket = 256 nodes
#define BSZ   256
#define CHUNK 8192     // edges per sort block
#define NBMAX 512      // max buckets supported (N <= 131072)

// ---------------- helpers ----------------

__device__ __forceinline__ void acc2(float& a, float& b, unsigned u) {
    a += __uint_as_float(u << 16);
    b += __uint_as_float(u & 0xffff0000u);
}

__device__ __forceinline__ void wsw_prep_one(int t,
        const float* wr1, const float* wo1, const float* wr2, const float* wo2,
        const float* wr3, const float* wo3, bf16* w1, bf16* w2, bf16* w3) {
    const int layer = t >> 12;
    t &= 4095;
    const float* wrel  = (layer == 0) ? wr1 : (layer == 1) ? wr2 : wr3;
    const float* wroot = (layer == 0) ? wo1 : (layer == 1) ? wo2 : wo3;
    bf16*        wsw   = (layer == 0) ? w1  : (layer == 1) ? w2  : w3;
    const int lane = t & 63;
    const int ct   = (t >> 6) & 7;
    const int kt   = t >> 9;
    const int kbase = kt * 32 + (lane >> 4) * 8;
    const int n     = ct * 16 + (lane & 15);
    bf16* q = wsw + (size_t)t * 8;
#pragma unroll
    for (int j = 0; j < 8; ++j) {
        const int k = kbase + j;
        const float v = (k < 128) ? wrel[k * 128 + n] : wroot[(k - 128) * 128 + n];
        q[j] = __float2bfloat16(v);
    }
}

// ==================================================================
// ====== cooperative fused front-end (prep + CSR build) ============
// ==================================================================
// Replaces 5 serial low-occupancy dispatches (prep_bhist, scan1, scan2,
// bscatter, bbuild) with ONE cooperative dispatch: all phases are
// occupancy-HOMOGENEOUS (<=32 VGPR, tiny LDS) so no register-inheritance
// trap (round-3 lesson). 4 grid.syncs on a small 512-block grid are far
// cheaper than 4 inter-dispatch gaps. agg/gemm stay separate (proven).

struct FrontArgs {
    const float* x;
    const int*   ei;
    const float *wr1, *wo1, *wr2, *wo2, *wr3, *wo3;
    bf16 *xbf, *wsw1, *wsw2, *wsw3;
    int  *T, *bsum, *rp, *col, *ebuf;
    int N, E, NB, GB, nT;
};

__global__ __launch_bounds__(256)
void front_kernel(FrontArgs a) {
    namespace cg = cooperative_groups;
    cg::grid_group grid = cg::this_grid();
    __shared__ int lh[NBMAX];     // hist / cursor / lrank
    __shared__ int ls[256];       // scan scratch

    const int tid  = threadIdx.x;
    const int G    = gridDim.x;
    const int gtid = blockIdx.x * 256 + tid;
    const int gsz  = G * 256;
    const int* src = a.ei;
    const int* dst = a.ei + a.E;

    // ---- Phase A1: cvt x -> xbf (row-major bf16, float4-vectorized) ----
    const int n4 = a.N * 32;
    for (int i = gtid; i < n4; i += gsz) {
        float4 v = ((const float4*)a.x)[i];
        bf162 p, q;
        p.x = __float2bfloat16(v.x); p.y = __float2bfloat16(v.y);
        q.x = __float2bfloat16(v.z); q.y = __float2bfloat16(v.w);
        ((bf162*)a.xbf)[i * 2]     = p;
        ((bf162*)a.xbf)[i * 2 + 1] = q;
    }
    // ---- Phase A2: weight swizzle (3 x 4096 items) ----
    for (int t = gtid; t < 3 * 4096; t += gsz)
        wsw_prep_one(t, a.wr1, a.wo1, a.wr2, a.wo2, a.wr3, a.wo3,
                     a.wsw1, a.wsw2, a.wsw3);
    // ---- Phase A3: per-chunk bucket histogram (grid-stride chunks) ----
    for (int c = blockIdx.x; c < a.GB; c += G) {
        for (int u = tid; u < a.NB; u += 256) lh[u] = 0;
        __syncthreads();
        const int beg = c * CHUNK, end = min(beg + CHUNK, a.E);
        for (int e = beg + tid; e < end; e += 256)
            atomicAdd(&lh[dst[e] >> BSH], 1);
        __syncthreads();
        for (int u = tid; u < a.NB; u += 256) a.T[u * a.GB + c] = lh[u];
        __syncthreads();
    }
    grid.sync();

    // ---- Phase B: scan1 -- 256-chunk exclusive scans of T in place ----
    const int nChunk = (a.nT + 255) >> 8;
    for (int c = blockIdx.x; c < nChunk; c += G) {
        const int i = c * 256 + tid;
        const int d = (i < a.nT) ? a.T[i] : 0;
        ls[tid] = d;
        __syncthreads();
        for (int off = 1; off < 256; off <<= 1) {
            int u = (tid >= off) ? ls[tid - off] : 0;
            __syncthreads();
            ls[tid] += u;
            __syncthreads();
        }
        if (i < a.nT) a.T[i] = ls[tid] - d;
        if (tid == 255) a.bsum[c] = ls[255];
        __syncthreads();
    }
    grid.sync();

    // ---- Phase C: block 0 exclusive-scans the chunk partials ----
    if (blockIdx.x == 0) {
        int carry = 0;
        for (int off = 0; off < nChunk; off += 256) {
            const int i = off + tid;
            const int v = (i < nChunk) ? a.bsum[i] : 0;
            ls[tid] = v;
            __syncthreads();
            for (int d2 = 1; d2 < 256; d2 <<= 1) {
                int u = (tid >= d2) ? ls[tid - d2] : 0;
                __syncthreads();
                ls[tid] += u;
                __syncthreads();
            }
            if (i < nChunk) a.bsum[i] = carry + ls[tid] - v;
            const int tot = ls[255];
            __syncthreads();
            carry += tot;
        }
    }
    grid.sync();

    // ---- Phase D: bscatter (grid-stride chunks; Tfinal = T + bsum[idx>>8]) ----
    for (int c = blockIdx.x; c < a.GB; c += G) {
        for (int u = tid; u < a.NB; u += 256) {
            const int idx = u * a.GB + c;
            lh[u] = a.T[idx] + a.bsum[idx >> 8];
        }
        __syncthreads();
        const int beg = c * CHUNK, end = min(beg + CHUNK, a.E);
        for (int e = beg + tid; e < end; e += 256) {
            const int d = dst[e];
            const int u = d >> BSH;
            const int pos = atomicAdd(&lh[u], 1);
            a.ebuf[pos] = (src[e] << BSH) | (d & (BSZ - 1));
        }
        __syncthreads();
    }
    grid.sync();

    // ---- Phase E: bbuild (grid-stride buckets) ----
    for (int u = blockIdx.x; u < a.NB; u += G) {
        const int i0 = u * a.GB;
        const int beg = a.T[i0] + a.bsum[i0 >> 8];
        const int i1 = (u + 1) * a.GB;
        const int end = (u + 1 < a.NB) ? (a.T[i1] + a.bsum[i1 >> 8]) : a.E;
        lh[tid] = 0;
        __syncthreads();
        for (int e = beg + tid; e < end; e += 256)
            atomicAdd(&lh[a.ebuf[e] & (BSZ - 1)], 1);
        __syncthreads();
        const int cntv = lh[tid];
        ls[tid] = cntv;
        __syncthreads();
        for (int off = 1; off < 256; off <<= 1) {
            int v = (tid >= off) ? ls[tid - off] : 0;
            __syncthreads();
            ls[tid] += v;
            __syncthreads();
        }
        const int excl = ls[tid] - cntv;
        const int node = u * BSZ + tid;
        if (node < a.N) a.rp[node] = beg + excl;
        if (u == a.NB - 1 && tid == 0) a.rp[a.N] = a.E;
        __syncthreads();
        lh[tid] = beg + excl;
        __syncthreads();
        for (int e = beg + tid; e < end; e += 256) {
            const int p = a.ebuf[e];
            const int pos = atomicAdd(&lh[p & (BSZ - 1)], 1);
            a.col[pos] = p >> BSH;
        }
        __syncthreads();
    }
}

// ==================================================================
// ====== fallback multi-kernel front-end (round-4 path) ============
// ==================================================================

__global__ __launch_bounds__(256)
void prep_bhist_kernel(const float* __restrict__ x, bf16* __restrict__ y, int n4, int nCvt,
                       const float* __restrict__ wr1, const float* __restrict__ wo1,
                       const float* __restrict__ wr2, const float* __restrict__ wo2,
                       const float* __restrict__ wr3, const float* __restrict__ wo3,
                       bf16* __restrict__ w1, bf16* __restrict__ w2, bf16* __restrict__ w3,
                       const int* __restrict__ dst, int* __restrict__ T,
                       int E, int NB, int GB) {
    __shared__ int lh[NBMAX];
    const int b = blockIdx.x;
    if (b < nCvt) {
        const int i = b * 256 + threadIdx.x;
        if (i < n4) {
            float4 v = ((const float4*)x)[i];
            bf162 a, c;
            a.x = __float2bfloat16(v.x); a.y = __float2bfloat16(v.y);
            c.x = __float2bfloat16(v.z); c.y = __float2bfloat16(v.w);
            ((bf162*)y)[i * 2]     = a;
            ((bf162*)y)[i * 2 + 1] = c;
        }
        return;
    }
    if (b < nCvt + 48) {
        wsw_prep_one((b - nCvt) * 256 + threadIdx.x,
                     wr1, wo1, wr2, wo2, wr3, wo3, w1, w2, w3);
        return;
    }
    const int bb = b - nCvt - 48;
    for (int u = threadIdx.x; u < NB; u += 256) lh[u] = 0;
    __syncthreads();
    const int beg = bb * CHUNK, end = min(beg + CHUNK, E);
    for (int e = beg + threadIdx.x; e < end; e += 256)
        atomicAdd(&lh[dst[e] >> BSH], 1);
    __syncthreads();
    for (int u = threadIdx.x; u < NB; u += 256)
        T[u * GB + bb] = lh[u];
}

__global__ __launch_bounds__(256)
void scan1_kernel(const int* __restrict__ deg, int* __restrict__ rp,
                  int* __restrict__ bsum, int n) {
    __shared__ int s[256];
    const int tid = threadIdx.x;
    const int i = blockIdx.x * 256 + tid;
    const int d = (i < n) ? deg[i] : 0;
    s[tid] = d;
    __syncthreads();
    for (int off = 1; off < 256; off <<= 1) {
        int u = (tid >= off) ? s[tid - off] : 0;
        __syncthreads();
        s[tid] += u;
        __syncthreads();
    }
    if (i < n) rp[i] = s[tid] - d;
    if (tid == 255) bsum[blockIdx.x] = s[255];
}

__global__ __launch_bounds__(512)
void scan2_kernel(int* __restrict__ bsum, int G) {
    __shared__ int s[512];
    const int tid = threadIdx.x;
    const int d = (tid < G) ? bsum[tid] : 0;
    s[tid] = d;
    __syncthreads();
    for (int off = 1; off < 512; off <<= 1) {
        int u = (tid >= off) ? s[tid - off] : 0;
        __syncthreads();
        s[tid] += u;
        __syncthreads();
    }
    if (tid < G) bsum[tid] = s[tid] - d;
}

__global__ __launch_bounds__(256)
void bscatter_kernel(const int* __restrict__ src, const int* __restrict__ dst,
                     const int* __restrict__ T, const int* __restrict__ bsum,
                     int* __restrict__ ebuf, int E, int NB, int GB) {
    __shared__ int lofs[NBMAX];
    const int b = blockIdx.x;
    for (int u = threadIdx.x; u < NB; u += 256) {
        const int idx = u * GB + b;
        lofs[u] = T[idx] + bsum[idx >> 8];
    }
    __syncthreads();
    const int beg = b * CHUNK, end = min(beg + CHUNK, E);
    for (int e = beg + threadIdx.x; e < end; e += 256) {
        const int d = dst[e];
        const int u = d >> BSH;
        const int pos = atomicAdd(&lofs[u], 1);
        ebuf[pos] = (src[e] << BSH) | (d & (BSZ - 1));
    }
}

__global__ __launch_bounds__(256)
void bbuild_kernel(const int* __restrict__ T, const int* __restrict__ bsum,
                   const int* __restrict__ ebuf,
                   int* __restrict__ rp, int* __restrict__ col,
                   int E, int N, int NB, int GB) {
    __shared__ int s[256];
    __shared__ int lrank[256];
    const int u = blockIdx.x;
    const int tid = threadIdx.x;
    const int i0 = u * GB;
    const int beg = T[i0] + bsum[i0 >> 8];
    const int i1 = (u + 1) * GB;
    const int end = (u + 1 < NB) ? (T[i1] + bsum[i1 >> 8]) : E;

    lrank[tid] = 0;
    __syncthreads();
    for (int e = beg + tid; e < end; e += 256)
        atomicAdd(&lrank[ebuf[e] & (BSZ - 1)], 1);
    __syncthreads();
    const int cntv = lrank[tid];
    s[tid] = cntv;
    __syncthreads();
    for (int off = 1; off < 256; off <<= 1) {
        int v = (tid >= off) ? s[tid - off] : 0;
        __syncthreads();
        s[tid] += v;
        __syncthreads();
    }
    const int excl = s[tid] - cntv;
    const int node = u * BSZ + tid;
    if (node < N) rp[node] = beg + excl;
    if (u == NB - 1 && tid == 0) rp[N] = E;
    lrank[tid] = beg + excl;
    __syncthreads();
    for (int e = beg + tid; e < end; e += 256) {
        const int p = ebuf[e];
        const int pos = atomicAdd(&lrank[p & (BSZ - 1)], 1);
        col[pos] = p >> BSH;
    }
}

// ---------------- aggregation (CSR, atomic-free, bf16, row-major) ----------------
// PROVEN 64 us / ~175 MB (gather service-rate-bound; five attack strategies null).
// one wave per node; lanes 0-31 own features l32*4..+3 of even edges, lanes
// 32-63 of odd edges; dwordx2 per lane = 2 rows/instruction; shfl_xor(32) combine.

__global__ __launch_bounds__(512)
void agg_kernel(const bf16* __restrict__ h, const int* __restrict__ rp,
                const int* __restrict__ col, bf16* __restrict__ agg, int N) {
    const int lane = threadIdx.x & 63;
    const int wid  = threadIdx.x >> 6;
    const int node = blockIdx.x * 8 + wid;
    if (node >= N) return;
    const int half = lane >> 5;
    const int l32  = lane & 31;
    const int f    = l32 * 4;
    const int beg = rp[node], end = rp[node + 1];

    float acc[4] = {0.f, 0.f, 0.f, 0.f};
    int e = beg;
#pragma unroll 2
    for (; e + 8 <= end; e += 8) {
        const int s0 = col[e + half];
        const int s1 = col[e + 2 + half];
        const int s2 = col[e + 4 + half];
        const int s3 = col[e + 6 + half];
        const uint2 r0 = *(const uint2*)(h + (size_t)s0 * 128 + f);
        const uint2 r1 = *(const uint2*)(h + (size_t)s1 * 128 + f);
        const uint2 r2 = *(const uint2*)(h + (size_t)s2 * 128 + f);
        const uint2 r3 = *(const uint2*)(h + (size_t)s3 * 128 + f);
        acc2(acc[0], acc[1], r0.x); acc2(acc[2], acc[3], r0.y);
        acc2(acc[0], acc[1], r1.x); acc2(acc[2], acc[3], r1.y);
        acc2(acc[0], acc[1], r2.x); acc2(acc[2], acc[3], r2.y);
        acc2(acc[0], acc[1], r3.x); acc2(acc[2], acc[3], r3.y);
    }
    for (; e < end; e += 2) {
        const bool act = (e + half) < end;
        const int s = col[act ? (e + half) : e];
        const uint2 r = *(const uint2*)(h + (size_t)s * 128 + f);
        if (act) { acc2(acc[0], acc[1], r.x); acc2(acc[2], acc[3], r.y); }
    }
#pragma unroll
    for (int j = 0; j < 4; ++j)
        acc[j] += __shfl_xor(acc[j], 32, 64);
    if (half == 0) {
        bf162 o0, o1;
        o0.x = __float2bfloat16(acc[0]); o0.y = __float2bfloat16(acc[1]);
        o1.x = __float2bfloat16(acc[2]); o1.y = __float2bfloat16(acc[3]);
        bf162* q = (bf162*)(agg + (size_t)node * 128 + f);
        q[0] = o0;
        q[1] = o1;
    }
}

// ---------------- MFMA dual GEMM: out = [agg|h] @ Wsw + b (+relu) ----------------
// 512 threads, 128 rows/block; wsw staged once in LDS; epilogue via LDS tile.

template <bool RELU, typename OT>
__global__ __launch_bounds__(512, 4)
void mfma_gemm_kernel(const bf16* __restrict__ Aagg, const bf16* __restrict__ Hroot,
                      const bf16* __restrict__ wsw, const float* __restrict__ bias,
                      OT* __restrict__ out, int M) {
    __shared__ __align__(16) char smem[67584];
    const int tid = threadIdx.x;

#pragma unroll
    for (int i = 0; i < 8; ++i) {
        const int off = i * 8192 + tid * 16;
        *(float4*)(smem + off) = *(const float4*)((const char*)wsw + off);
    }
    __syncthreads();

    const int lane = tid & 63;
    const int wave = tid >> 6;
    const int l15  = lane & 15;
    const int quad = lane >> 4;
    const int base = blockIdx.x * 128;
    const int row_a = base + wave * 16 + l15;
    const bool rowok = row_a < M;
    const bf16* wl = (const bf16*)smem;

    floatx4 acc[8];
#pragma unroll
    for (int ct = 0; ct < 8; ++ct) acc[ct] = (floatx4){0.f, 0.f, 0.f, 0.f};

#pragma unroll
    for (int kt = 0; kt < 8; ++kt) {
        const bf16* Abase = (kt < 4) ? Aagg : Hroot;
        const int k0 = (kt & 3) * 32 + quad * 8;
        short8 afrag = (short8){0, 0, 0, 0, 0, 0, 0, 0};
        if (rowok) afrag = *(const short8*)(Abase + (size_t)row_a * 128 + k0);
#pragma unroll
        for (int ct = 0; ct < 8; ++ct) {
            const short8 bfrag = *(const short8*)(wl + (size_t)((kt * 8 + ct) * 64 + lane) * 8);
            acc[ct] = __builtin_amdgcn_mfma_f32_16x16x32_bf16(afrag, bfrag, acc[ct], 0, 0, 0);
        }
    }

    __syncthreads();   // all waves done reading wl -> reuse smem as output tile
    const int rloc = wave * 16 + quad * 4;

    if constexpr (sizeof(OT) == 2) {
        bf16* tl = (bf16*)smem;                // stride 136 bf16 = 272 B
#pragma unroll
        for (int ct = 0; ct < 8; ++ct) {
            const int colc = ct * 16 + l15;
            const float bv = bias[colc];
#pragma unroll
            for (int r = 0; r < 4; ++r) {
                float v = acc[ct][r] + bv;
                if (RELU) v = fmaxf(v, 0.f);
                tl[(rloc + r) * 136 + colc] = __float2bfloat16(v);
            }
        }
        __syncthreads();
#pragma unroll
        for (int i = 0; i < 4; ++i) {
            const int chunk = i * 512 + tid;
            const int row = chunk >> 4;
            const int c   = chunk & 15;
            if (base + row < M)
                *(float4*)((char*)out + (size_t)(base + row) * 256 + c * 16) =
                    *(const float4*)(smem + row * 272 + c * 16);
        }
    } else {
        float* tl = (float*)smem;              // stride 132 f32 = 528 B
#pragma unroll
        for (int ct = 0; ct < 8; ++ct) {
            const int colc = ct * 16 + l15;
            const float bv = bias[colc];
#pragma unroll
            for (int r = 0; r < 4; ++r) {
                float v = acc[ct][r] + bv;
                if (RELU) v = fmaxf(v, 0.f);
                tl[(rloc + r) * 132 + colc] = v;
            }
        }
        __syncthreads();
#pragma unroll
        for (int i = 0; i < 8; ++i) {
            const int chunk = i * 512 + tid;
            const int row = chunk >> 5;
            const int c   = chunk & 31;
            if (base + row < M)
                *(float4*)((char*)out + (size_t)(base + row) * 512 + c * 16) =
                    *(const float4*)(smem + row * 528 + c * 16);
        }
    }
}

// ---------------- launch ----------------

extern "C" void kernel_launch(void* const* d_in, const int* in_sizes, int n_in,
                              void* d_out, int out_size, void* d_ws, size_t ws_size,
                              hipStream_t stream) {
    const float* x       = (const float*)d_in[0];
    const int*   ei      = (const int*)d_in[1];
    const float* w_rel1  = (const float*)d_in[2];
    const float* w_root1 = (const float*)d_in[3];
    const float* b1      = (const float*)d_in[4];
    const float* w_rel2  = (const float*)d_in[5];
    const float* w_root2 = (const float*)d_in[6];
    const float* b2      = (const float*)d_in[7];
    const float* w_rel3  = (const float*)d_in[8];
    const float* w_root3 = (const float*)d_in[9];
    const float* b3      = (const float*)d_in[10];
    float* out = (float*)d_out;

    const int N = in_sizes[0] / 128;
    const int E = in_sizes[1] / 2;
    const int* src = ei;
    const int* dst = ei + E;

    // workspace layout (~84 MB)
    char* w = (char*)d_ws;
    auto alloc = [&](size_t bytes) {
        char* p = w;
        w += (bytes + 255) & ~(size_t)255;
        return p;
    };
    int*  col  = (int*)alloc((size_t)E * 4);            // 6.4 MB
    int*  rp   = (int*)alloc((size_t)(N + 1) * 4);      // 0.4 MB
    bf16* h1   = (bf16*)alloc((size_t)N * 128 * 2);     // 25.6 MB
    bf16* xbf  = (bf16*)alloc((size_t)N * 128 * 2);     // 25.6 MB (reused as h2)
    bf16* aggb = (bf16*)alloc((size_t)N * 128 * 2);     // 25.6 MB
    bf16* wsw1 = (bf16*)alloc(32768 * 2);               // 64 KB
    bf16* wsw2 = (bf16*)alloc(32768 * 2);
    bf16* wsw3 = (bf16*)alloc(32768 * 2);
    bf16* h2   = xbf;       // layer-2 output overwrites xbf (last read: layer-1 gemm)
    // CSR-build scratch aliases buffers written only AFTER the build completes:
    int*  T    = (int*)h1;                  // NB*GB ints (~306 KB) in h1's space
    int*  bsum = (int*)(h1 + 1024 * 1024);  // scan partials, past T
    int*  ebuf = (int*)aggb;                // E ints (6.4 MB) in aggb's space

    const int NB = (N + BSZ - 1) / BSZ;        // 391 buckets
    const int GB = (E + CHUNK - 1) / CHUNK;    // 196 sort blocks
    const int nT = NB * GB;                    // 76,636
    const int scanTBlocks = (nT + 255) / 256;  // 300 <= 512

    const int aggBlocks  = (N + 7) / 8;
    const int gemmBlocks = (N + 127) / 128;
    const int cvtBlocks  = (N * 32 + 255) / 256;

    // ---- front-end: cooperative fused path, multi-kernel fallback ----
    static int frontGrid = 0;
    if (frontGrid == 0) {
        int perCU = 0, nCU = 0, dev = 0;
        hipError_t e1 = hipGetDevice(&dev);
        hipError_t e2 = hipDeviceGetAttribute(&nCU, hipDeviceAttributeMultiprocessorCount, dev);
        hipError_t e3 = hipOccupancyMaxActiveBlocksPerMultiprocessor(&perCU, front_kernel, 256, 0);
        if (e1 == hipSuccess && e2 == hipSuccess && e3 == hipSuccess && perCU > 0 && nCU > 0) {
            frontGrid = perCU * nCU;
            if (frontGrid > 512) frontGrid = 512;
        } else {
            frontGrid = -1;
        }
    }

    bool frontDone = false;
    if (frontGrid > 0) {
        FrontArgs fa;
        fa.x = x; fa.ei = ei;
        fa.wr1 = w_rel1; fa.wo1 = w_root1; fa.wr2 = w_rel2; fa.wo2 = w_root2;
        fa.wr3 = w_rel3; fa.wo3 = w_root3;
        fa.xbf = xbf; fa.wsw1 = wsw1; fa.wsw2 = wsw2; fa.wsw3 = wsw3;
        fa.T = T; fa.bsum = bsum; fa.rp = rp; fa.col = col; fa.ebuf = ebuf;
        fa.N = N; fa.E = E; fa.NB = NB; fa.GB = GB; fa.nT = nT;
        void* args[] = {&fa};
        if (hipLaunchCooperativeKernel((const void*)front_kernel, dim3(frontGrid),
                                       dim3(256), args, 0, stream) == hipSuccess)
            frontDone = true;
    }
    if (!frontDone) {
        prep_bhist_kernel<<<cvtBlocks + 48 + GB, 256, 0, stream>>>(
            x, xbf, N * 32, cvtBlocks,
            w_rel1, w_root1, w_rel2, w_root2, w_rel3, w_root3,
            wsw1, wsw2, wsw3,
            dst, T, E, NB, GB);
        scan1_kernel<<<scanTBlocks, 256, 0, stream>>>(T, T, bsum, nT);
        scan2_kernel<<<1, 512, 0, stream>>>(bsum, scanTBlocks);
        bscatter_kernel<<<GB, 256, 0, stream>>>(src, dst, T, bsum, ebuf, E, NB, GB);
        bbuild_kernel<<<NB, 256, 0, stream>>>(T, bsum, ebuf, rp, col, E, N, NB, GB);
    }

    // layer 1
    agg_kernel<<<aggBlocks, 512, 0, stream>>>(xbf, rp, col, aggb, N);
    mfma_gemm_kernel<true, bf16><<<gemmBlocks, 512, 0, stream>>>(aggb, xbf, wsw1, b1, h1, N);
    // layer 2
    agg_kernel<<<aggBlocks, 512, 0, stream>>>(h1, rp, col, aggb, N);
    mfma_gemm_kernel<true, bf16><<<gemmBlocks, 512, 0, stream>>>(aggb, h1, wsw2, b2, h2, N);
    // layer 3
    agg_kernel<<<aggBlocks, 512, 0, stream>>>(h2, rp, col, aggb, N);
    mfma_gemm_kernel<false, float><<<gemmBlocks, 512, 0, stream>>>(aggb, h2, wsw3, b3, out, N);
}

// Round 10
// 425.501 us; speedup vs baseline: 1.5939x; 1.5939x over previous
//
#include <hip/hip_runtime.h>
#include <hip/hip_bf16.h>
#include <stdint.h>

typedef __hip_bfloat16 bf16;
typedef __hip_bfloat162 bf162;

typedef __attribute__((ext_vector_type(8))) short short8;   // 8 bf16 = 4 VGPRs
typedef __attribute__((ext_vector_type(4))) float floatx4;  // MFMA accumulator

#define BSH   8        // bucket = 256 nodes
#define BSZ   256
#define CHUNK 8192     // edges per sort block
#define NBMAX 512      // max buckets supported (N <= 131072)

// ---------------- helpers ----------------

__device__ __forceinline__ void acc2(float& a, float& b, unsigned u) {
    a += __uint_as_float(u << 16);
    b += __uint_as_float(u & 0xffff0000u);
}

// ---------------- prep + bhist (single dispatch) ----------------
// blocks [0, nCvt):        x -> bf16
// blocks [nCvt, nCvt+48):  weights -> B-fragment layout for mfma_f32_16x16x32_bf16:
//   wsw[((kt*8+ct)*64+lane)*8 + j] = W[kt*32 + (lane>>4)*8 + j][ct*16 + (lane&15)]
//   where W = concat_k(w_rel, w_root), 256x128 row-major.
// blocks [nCvt+48, ...):   per-chunk bucket histogram of dst (independent of cvt/wsw)
__global__ __launch_bounds__(256)
void prep_bhist_kernel(const float* __restrict__ x, bf16* __restrict__ y, int n4, int nCvt,
                       const float* __restrict__ wr1, const float* __restrict__ wo1,
                       const float* __restrict__ wr2, const float* __restrict__ wo2,
                       const float* __restrict__ wr3, const float* __restrict__ wo3,
                       bf16* __restrict__ w1, bf16* __restrict__ w2, bf16* __restrict__ w3,
                       const int* __restrict__ dst, int* __restrict__ T,
                       int E, int NB, int GB) {
    __shared__ int lh[NBMAX];
    const int b = blockIdx.x;
    if (b < nCvt) {
        const int i = b * 256 + threadIdx.x;
        if (i < n4) {
            float4 v = ((const float4*)x)[i];
            bf162 a, c;
            a.x = __float2bfloat16(v.x); a.y = __float2bfloat16(v.y);
            c.x = __float2bfloat16(v.z); c.y = __float2bfloat16(v.w);
            ((bf162*)y)[i * 2]     = a;
            ((bf162*)y)[i * 2 + 1] = c;
        }
        return;
    }
    if (b < nCvt + 48) {
        int t = (b - nCvt) * 256 + threadIdx.x;       // 0..12287
        const int layer = t >> 12;
        t &= 4095;
        const float* wrel  = (layer == 0) ? wr1 : (layer == 1) ? wr2 : wr3;
        const float* wroot = (layer == 0) ? wo1 : (layer == 1) ? wo2 : wo3;
        bf16*        wsw   = (layer == 0) ? w1  : (layer == 1) ? w2  : w3;
        const int lane = t & 63;
        const int ct   = (t >> 6) & 7;
        const int kt   = t >> 9;
        const int kbase = kt * 32 + (lane >> 4) * 8;
        const int n     = ct * 16 + (lane & 15);
        bf16* q = wsw + (size_t)t * 8;
#pragma unroll
        for (int j = 0; j < 8; ++j) {
            const int k = kbase + j;
            const float v = (k < 128) ? wrel[k * 128 + n] : wroot[(k - 128) * 128 + n];
            q[j] = __float2bfloat16(v);
        }
        return;
    }
    // ---- bhist ----
    const int bb = b - nCvt - 48;
    for (int u = threadIdx.x; u < NB; u += 256) lh[u] = 0;
    __syncthreads();
    const int beg = bb * CHUNK, end = min(beg + CHUNK, E);
    for (int e = beg + threadIdx.x; e < end; e += 256)
        atomicAdd(&lh[dst[e] >> BSH], 1);
    __syncthreads();
    for (int u = threadIdx.x; u < NB; u += 256)
        T[u * GB + bb] = lh[u];
}

// ---------------- CSR build: two-level counting sort ----------------

__global__ __launch_bounds__(256)
void scan1_kernel(const int* __restrict__ deg, int* __restrict__ rp,
                  int* __restrict__ bsum, int n) {
    __shared__ int s[256];
    const int tid = threadIdx.x;
    const int i = blockIdx.x * 256 + tid;
    const int d = (i < n) ? deg[i] : 0;
    s[tid] = d;
    __syncthreads();
    for (int off = 1; off < 256; off <<= 1) {
        int u = (tid >= off) ? s[tid - off] : 0;
        __syncthreads();
        s[tid] += u;
        __syncthreads();
    }
    if (i < n) rp[i] = s[tid] - d;
    if (tid == 255) bsum[blockIdx.x] = s[255];
}

__global__ __launch_bounds__(512)
void scan2_kernel(int* __restrict__ bsum, int G) {
    __shared__ int s[512];
    const int tid = threadIdx.x;
    const int d = (tid < G) ? bsum[tid] : 0;
    s[tid] = d;
    __syncthreads();
    for (int off = 1; off < 512; off <<= 1) {
        int u = (tid >= off) ? s[tid - off] : 0;
        __syncthreads();
        s[tid] += u;
        __syncthreads();
    }
    if (tid < G) bsum[tid] = s[tid] - d;
}

// scan3 folded into the two consumers: Tfinal[i] = T[i] + bsum[i >> 8]

__global__ __launch_bounds__(256)
void bscatter_kernel(const int* __restrict__ src, const int* __restrict__ dst,
                     const int* __restrict__ T, const int* __restrict__ bsum,
                     int* __restrict__ ebuf, int E, int NB, int GB) {
    __shared__ int lofs[NBMAX];
    const int b = blockIdx.x;
    for (int u = threadIdx.x; u < NB; u += 256) {
        const int idx = u * GB + b;
        lofs[u] = T[idx] + bsum[idx >> 8];
    }
    __syncthreads();
    const int beg = b * CHUNK, end = min(beg + CHUNK, E);
    for (int e = beg + threadIdx.x; e < end; e += 256) {
        const int d = dst[e];
        const int u = d >> BSH;
        const int pos = atomicAdd(&lofs[u], 1);
        ebuf[pos] = (src[e] << BSH) | (d & (BSZ - 1));
    }
}

__global__ __launch_bounds__(256)
void bbuild_kernel(const int* __restrict__ T, const int* __restrict__ bsum,
                   const int* __restrict__ ebuf,
                   int* __restrict__ rp, int* __restrict__ col,
                   int E, int N, int NB, int GB) {
    __shared__ int s[256];
    __shared__ int lrank[256];
    const int u = blockIdx.x;
    const int tid = threadIdx.x;
    const int i0 = u * GB;
    const int beg = T[i0] + bsum[i0 >> 8];
    const int i1 = (u + 1) * GB;
    const int end = (u + 1 < NB) ? (T[i1] + bsum[i1 >> 8]) : E;

    lrank[tid] = 0;
    __syncthreads();
    for (int e = beg + tid; e < end; e += 256)
        atomicAdd(&lrank[ebuf[e] & (BSZ - 1)], 1);
    __syncthreads();
    const int cntv = lrank[tid];
    s[tid] = cntv;
    __syncthreads();
    for (int off = 1; off < 256; off <<= 1) {
        int v = (tid >= off) ? s[tid - off] : 0;
        __syncthreads();
        s[tid] += v;
        __syncthreads();
    }
    const int excl = s[tid] - cntv;
    const int node = u * BSZ + tid;
    if (node < N) rp[node] = beg + excl;
    if (u == NB - 1 && tid == 0) rp[N] = E;
    lrank[tid] = beg + excl;
    __syncthreads();
    for (int e = beg + tid; e < end; e += 256) {
        const int p = ebuf[e];
        const int pos = atomicAdd(&lrank[p & (BSZ - 1)], 1);
        col[pos] = p >> BSH;
    }
}

// ---------------- aggregation (CSR, atomic-free, bf16) ----------------
// PROVEN 64 us / 176 MB (L3 random-line service-rate bound; six attack
// strategies null or negative). one wave per node; lanes 0-31 own features
// l32*4..+3 of even edges, lanes 32-63 of odd edges; dwordx2 per lane =
// 2 rows/instruction; shfl_xor(32) combine.

__global__ __launch_bounds__(512)
void agg_kernel(const bf16* __restrict__ h, const int* __restrict__ rp,
                const int* __restrict__ col, bf16* __restrict__ agg, int N) {
    const int lane = threadIdx.x & 63;
    const int wid  = threadIdx.x >> 6;
    const int node = blockIdx.x * 8 + wid;
    if (node >= N) return;
    const int half = lane >> 5;
    const int l32  = lane & 31;
    const int f    = l32 * 4;
    const int beg = rp[node], end = rp[node + 1];

    float acc[4] = {0.f, 0.f, 0.f, 0.f};
    int e = beg;
#pragma unroll 2
    for (; e + 8 <= end; e += 8) {
        const int s0 = col[e + half];
        const int s1 = col[e + 2 + half];
        const int s2 = col[e + 4 + half];
        const int s3 = col[e + 6 + half];
        const uint2 r0 = *(const uint2*)(h + (size_t)s0 * 128 + f);
        const uint2 r1 = *(const uint2*)(h + (size_t)s1 * 128 + f);
        const uint2 r2 = *(const uint2*)(h + (size_t)s2 * 128 + f);
        const uint2 r3 = *(const uint2*)(h + (size_t)s3 * 128 + f);
        acc2(acc[0], acc[1], r0.x); acc2(acc[2], acc[3], r0.y);
        acc2(acc[0], acc[1], r1.x); acc2(acc[2], acc[3], r1.y);
        acc2(acc[0], acc[1], r2.x); acc2(acc[2], acc[3], r2.y);
        acc2(acc[0], acc[1], r3.x); acc2(acc[2], acc[3], r3.y);
    }
    for (; e < end; e += 2) {
        const bool act = (e + half) < end;
        const int s = col[act ? (e + half) : e];
        const uint2 r = *(const uint2*)(h + (size_t)s * 128 + f);
        if (act) { acc2(acc[0], acc[1], r.x); acc2(acc[2], acc[3], r.y); }
    }
#pragma unroll
    for (int j = 0; j < 4; ++j)
        acc[j] += __shfl_xor(acc[j], 32, 64);
    if (half == 0) {
        bf162 o0, o1;
        o0.x = __float2bfloat16(acc[0]); o0.y = __float2bfloat16(acc[1]);
        o1.x = __float2bfloat16(acc[2]); o1.y = __float2bfloat16(acc[3]);
        bf162* q = (bf162*)(agg + (size_t)node * 128 + f);
        q[0] = o0;
        q[1] = o1;
    }
}

// ---------------- MFMA dual GEMM: out = [agg|h] @ Wsw + b (+relu) ----------------
// 512 threads, 128 rows/block. wsw (64 KB) staged ONCE into LDS per block
// (kills per-wave global B re-reads); epilogue routed through an LDS tile
// (padded stride) then written with coalesced dwordx4 (kills scattered 2-byte
// stores). LDS 66 KB -> 2 blocks/CU, 16 waves/CU.

template <bool RELU, typename OT>
__global__ __launch_bounds__(512)
void mfma_gemm_kernel(const bf16* __restrict__ Aagg, const bf16* __restrict__ Hroot,
                      const bf16* __restrict__ wsw, const float* __restrict__ bias,
                      OT* __restrict__ out, int M) {
    __shared__ __align__(16) char smem[67584];
    const int tid = threadIdx.x;

    // stage all B-fragments (65536 B) into LDS: 512 thr x 16 B x 8
#pragma unroll
    for (int i = 0; i < 8; ++i) {
        const int off = i * 8192 + tid * 16;
        *(float4*)(smem + off) = *(const float4*)((const char*)wsw + off);
    }
    __syncthreads();

    const int lane = tid & 63;
    const int wave = tid >> 6;
    const int l15  = lane & 15;
    const int quad = lane >> 4;
    const int base = blockIdx.x * 128;
    const int row_a = base + wave * 16 + l15;
    const bool rowok = row_a < M;
    const bf16* wl = (const bf16*)smem;

    floatx4 acc[8];
#pragma unroll
    for (int ct = 0; ct < 8; ++ct) acc[ct] = (floatx4){0.f, 0.f, 0.f, 0.f};

#pragma unroll
    for (int kt = 0; kt < 8; ++kt) {
        const bf16* Abase = (kt < 4) ? Aagg : Hroot;
        const int k0 = (kt & 3) * 32 + quad * 8;
        short8 afrag = (short8){0, 0, 0, 0, 0, 0, 0, 0};
        if (rowok) afrag = *(const short8*)(Abase + (size_t)row_a * 128 + k0);
#pragma unroll
        for (int ct = 0; ct < 8; ++ct) {
            const short8 bfrag = *(const short8*)(wl + (size_t)((kt * 8 + ct) * 64 + lane) * 8);
            acc[ct] = __builtin_amdgcn_mfma_f32_16x16x32_bf16(afrag, bfrag, acc[ct], 0, 0, 0);
        }
    }

    __syncthreads();   // all waves done reading wl -> reuse smem as output tile
    const int rloc = wave * 16 + quad * 4;

    if constexpr (sizeof(OT) == 2) {
        bf16* tl = (bf16*)smem;                // stride 136 bf16 = 272 B (16-aligned)
#pragma unroll
        for (int ct = 0; ct < 8; ++ct) {
            const int colc = ct * 16 + l15;
            const float bv = bias[colc];
#pragma unroll
            for (int r = 0; r < 4; ++r) {
                float v = acc[ct][r] + bv;
                if (RELU) v = fmaxf(v, 0.f);
                tl[(rloc + r) * 136 + colc] = __float2bfloat16(v);
            }
        }
        __syncthreads();
        // 128 rows x 256 B out, coalesced dwordx4: 2048 chunks / 512 thr
#pragma unroll
        for (int i = 0; i < 4; ++i) {
            const int chunk = i * 512 + tid;
            const int row = chunk >> 4;
            const int c   = chunk & 15;
            if (base + row < M)
                *(float4*)((char*)out + (size_t)(base + row) * 256 + c * 16) =
                    *(const float4*)(smem + row * 272 + c * 16);
        }
    } else {
        float* tl = (float*)smem;              // stride 132 f32 = 528 B (16-aligned)
#pragma unroll
        for (int ct = 0; ct < 8; ++ct) {
            const int colc = ct * 16 + l15;
            const float bv = bias[colc];
#pragma unroll
            for (int r = 0; r < 4; ++r) {
                float v = acc[ct][r] + bv;
                if (RELU) v = fmaxf(v, 0.f);
                tl[(rloc + r) * 132 + colc] = v;
            }
        }
        __syncthreads();
        // 128 rows x 512 B out: 4096 chunks / 512 thr
#pragma unroll
        for (int i = 0; i < 8; ++i) {
            const int chunk = i * 512 + tid;
            const int row = chunk >> 5;
            const int c   = chunk & 31;
            if (base + row < M)
                *(float4*)((char*)out + (size_t)(base + row) * 512 + c * 16) =
                    *(const float4*)(smem + row * 528 + c * 16);
        }
    }
}

// ---------------- launch ----------------

extern "C" void kernel_launch(void* const* d_in, const int* in_sizes, int n_in,
                              void* d_out, int out_size, void* d_ws, size_t ws_size,
                              hipStream_t stream) {
    const float* x       = (const float*)d_in[0];
    const int*   ei      = (const int*)d_in[1];
    const float* w_rel1  = (const float*)d_in[2];
    const float* w_root1 = (const float*)d_in[3];
    const float* b1      = (const float*)d_in[4];
    const float* w_rel2  = (const float*)d_in[5];
    const float* w_root2 = (const float*)d_in[6];
    const float* b2      = (const float*)d_in[7];
    const float* w_rel3  = (const float*)d_in[8];
    const float* w_root3 = (const float*)d_in[9];
    const float* b3      = (const float*)d_in[10];
    float* out = (float*)d_out;

    const int N = in_sizes[0] / 128;
    const int E = in_sizes[1] / 2;
    const int* src = ei;
    const int* dst = ei + E;

    // workspace layout (~84 MB)
    char* w = (char*)d_ws;
    auto alloc = [&](size_t bytes) {
        char* p = w;
        w += (bytes + 255) & ~(size_t)255;
        return p;
    };
    int*  col  = (int*)alloc((size_t)E * 4);            // 6.4 MB
    int*  rp   = (int*)alloc((size_t)(N + 1) * 4);      // 0.4 MB
    bf16* h1   = (bf16*)alloc((size_t)N * 128 * 2);     // 25.6 MB
    bf16* xbf  = (bf16*)alloc((size_t)N * 128 * 2);     // 25.6 MB (reused as h2)
    bf16* aggb = (bf16*)alloc((size_t)N * 128 * 2);     // 25.6 MB
    bf16* wsw1 = (bf16*)alloc(32768 * 2);               // 64 KB
    bf16* wsw2 = (bf16*)alloc(32768 * 2);
    bf16* wsw3 = (bf16*)alloc(32768 * 2);
    bf16* h2   = xbf;       // layer-2 output overwrites xbf (last read: layer-1 gemm)
    // CSR-build scratch aliases buffers written only AFTER the build completes:
    int*  T    = (int*)h1;                  // NB*GB ints (~306 KB) in h1's space
    int*  bsum = (int*)(h1 + 1024 * 1024);  // scan partials, past T
    int*  ebuf = (int*)aggb;                // E ints (6.4 MB) in aggb's space

    const int NB = (N + BSZ - 1) / BSZ;        // 391 buckets
    const int GB = (E + CHUNK - 1) / CHUNK;    // 196 sort blocks
    const int nT = NB * GB;                    // 76,636
    const int scanTBlocks = (nT + 255) / 256;  // 300 <= 512

    const int aggBlocks  = (N + 7) / 8;
    const int gemmBlocks = (N + 127) / 128;
    const int cvtBlocks  = (N * 32 + 255) / 256;

    // prep (cvt + wsw) and bhist: independent work, one dispatch
    prep_bhist_kernel<<<cvtBlocks + 48 + GB, 256, 0, stream>>>(
        x, xbf, N * 32, cvtBlocks,
        w_rel1, w_root1, w_rel2, w_root2, w_rel3, w_root3,
        wsw1, wsw2, wsw3,
        dst, T, E, NB, GB);

    // CSR by dst: two-level counting sort (scan3 folded into consumers)
    scan1_kernel<<<scanTBlocks, 256, 0, stream>>>(T, T, bsum, nT);
    scan2_kernel<<<1, 512, 0, stream>>>(bsum, scanTBlocks);
    bscatter_kernel<<<GB, 256, 0, stream>>>(src, dst, T, bsum, ebuf, E, NB, GB);
    bbuild_kernel<<<NB, 256, 0, stream>>>(T, bsum, ebuf, rp, col, E, N, NB, GB);

    // layer 1
    agg_kernel<<<aggBlocks, 512, 0, stream>>>(xbf, rp, col, aggb, N);
    mfma_gemm_kernel<true, bf16><<<gemmBlocks, 512, 0, stream>>>(aggb, xbf, wsw1, b1, h1, N);
    // layer 2
    agg_kernel<<<aggBlocks, 512, 0, stream>>>(h1, rp, col, aggb, N);
    mfma_gemm_kernel<true, bf16><<<gemmBlocks, 512, 0, stream>>>(aggb, h1, wsw2, b2, h2, N);
    // layer 3
    agg_kernel<<<aggBlocks, 512, 0, stream>>>(h2, rp, col, aggb, N);
    mfma_gemm_kernel<false, float><<<gemmBlocks, 512, 0, stream>>>(aggb, h2, wsw3, b3, out, N);
}